// Round 1
// baseline (1212.409 us; speedup 1.0000x reference)
//
#include <hip/hip_runtime.h>

#define NC 3
#define NPC 16
#define NHID 64
#define IMH 128
#define IMW 128
#define NB 32
#define CIN 19        // NC + NPC
#define KSZ 171       // CIN * 9

__device__ __forceinline__ float logsig(float z) {
    // log_sigmoid(z) = min(z,0) - log1p(exp(-|z|))
    return fminf(z, 0.f) - log1pf(expf(-fabsf(z)));
}

__global__ __launch_bounds__(256) void pcnn_lp_kernel(
    const float* __restrict__ value, const float* __restrict__ dp,
    const float* __restrict__ W1, const float* __restrict__ b1,
    const float* __restrict__ W2, const float* __restrict__ b2,
    float* __restrict__ out)
{
    const int bi  = blockIdx.x;
    const int tid = threadIdx.x;

    // ---- decode block -> (eval e, batch b, tile), level geometry ----
    int e, b, tile, gw, r, rows_per_tile;
    if (bi < 96)            { e = bi >> 5;            b = bi & 31;              tile = 0;         gw = 32;  r = 4; rows_per_tile = 16; }
    else if (bi < 1248)     { int u = bi - 96;   e = 3  + (u >> 7); int rem = u & 127; b = rem >> 2; tile = rem & 3;  gw = 64;  r = 2; rows_per_tile = 8; }
    else                    { int u = bi - 1248; e = 12 + (u >> 9); int rem = u & 511; b = rem >> 4; tile = rem & 15; gw = 128; r = 1; rows_per_tile = 4; }

    const int ow = gw >> 1;                 // slice-grid width
    const int oy = tile * rows_per_tile + tid / ow;
    const int ox = tid % ow;

    // ---- eval -> slice parity, channel index, sub-block index ----
    int sy0, sx0, cch, s_idx;
    if (e < 3) { sy0 = 0; sx0 = 0; cch = e; s_idx = -1; }
    else {
        int u = e - 3; int s = (u % 9) / 3; cch = u % 3; s_idx = s;
        sy0 = (s == 1) ? 0 : 1;
        sx0 = (s == 2) ? 0 : 1;
    }
    const int y0 = sy0 + 2 * oy;            // level-grid coords of scored pixel
    const int x0 = sx0 + 2 * ox;
    const int net = e;                      // net index == eval index (verified)

    // mask-active test for value channel ch at level-grid parity (py,px)
    auto activef = [&](int ch, int py, int px) -> bool {
        if (e < 3) return (py == 0 && px == 0) && (ch < cch);
        if (py == 0 && px == 0) return true;  // base pixels of this level
        int sp = (py == 1 && px == 1) ? 0 : ((py == 0 && px == 1) ? 1 : 2);
        return (sp < s_idx) || (sp == s_idx && ch < cch);
    };

    // ---- hidden accumulators ----
    float acc[NHID];
    const float* b1n = b1 + net * NHID;
    #pragma unroll
    for (int k = 0; k < NHID; ++k) acc[k] = b1n[k];

    const float* W1n = W1 + net * NHID * KSZ;
    const float* vb  = value + (size_t)b * NC  * IMH * IMW;
    const float* pb  = dp    + (size_t)b * NPC * IMH * IMW;

    // ---- value channels (masked) ----
    #pragma unroll
    for (int ci = 0; ci < NC; ++ci) {
        float p[9];
        #pragma unroll
        for (int dy = 0; dy < 3; ++dy) {
            const int yy = y0 + dy - 1;
            const bool vy = (yy >= 0) && (yy < gw);
            #pragma unroll
            for (int dx = 0; dx < 3; ++dx) {
                const int xx = x0 + dx - 1;
                const bool vx = (xx >= 0) && (xx < gw);
                float v = 0.f;
                if (vy && vx && activef(ci, (sy0 + dy - 1) & 1, (sx0 + dx - 1) & 1))
                    v = vb[(ci * IMH + yy * r) * IMW + xx * r];
                p[dy * 3 + dx] = v;
            }
        }
        const float* w = W1n + ci * 9;
        #pragma unroll
        for (int k = 0; k < NHID; ++k) {
            #pragma unroll
            for (int j = 0; j < 9; ++j) acc[k] += w[k * KSZ + j] * p[j];
        }
    }

    // ---- distribution-param channels (unmasked) ----
    for (int q = 0; q < NPC; ++q) {
        float p[9];
        #pragma unroll
        for (int dy = 0; dy < 3; ++dy) {
            const int yy = y0 + dy - 1;
            const bool vy = (yy >= 0) && (yy < gw);
            #pragma unroll
            for (int dx = 0; dx < 3; ++dx) {
                const int xx = x0 + dx - 1;
                const bool vx = (xx >= 0) && (xx < gw);
                float v = 0.f;
                if (vy && vx)
                    v = pb[(q * IMH + yy * r) * IMW + xx * r];
                p[dy * 3 + dx] = v;
            }
        }
        const float* w = W1n + (NC + q) * 9;
        #pragma unroll
        for (int k = 0; k < NHID; ++k) {
            #pragma unroll
            for (int j = 0; j < 9; ++j) acc[k] += w[k * KSZ + j] * p[j];
        }
    }

    // ---- 1x1 conv + log-prob term ----
    const float* W2n = W2 + net * NHID;
    float z = b2[net];
    #pragma unroll
    for (int k = 0; k < NHID; ++k) z += W2n[k] * fmaxf(acc[k], 0.f);

    const float x = vb[(cch * IMH + y0 * r) * IMW + x0 * r];
    float term = x * logsig(z) + (1.f - x) * logsig(-z);

    // ---- reduce: wave shuffle -> LDS -> one atomic per block ----
    #pragma unroll
    for (int off = 32; off > 0; off >>= 1) term += __shfl_down(term, off);
    __shared__ float wsum[4];
    if ((tid & 63) == 0) wsum[tid >> 6] = term;
    __syncthreads();
    if (tid == 0) {
        atomicAdd(out, wsum[0] + wsum[1] + wsum[2] + wsum[3]);
    }
}

extern "C" void kernel_launch(void* const* d_in, const int* in_sizes, int n_in,
                              void* d_out, int out_size, void* d_ws, size_t ws_size,
                              hipStream_t stream) {
    const float* value = (const float*)d_in[0];
    const float* dp    = (const float*)d_in[1];
    const float* W1    = (const float*)d_in[2];
    const float* b1    = (const float*)d_in[3];
    const float* W2    = (const float*)d_in[4];
    const float* b2    = (const float*)d_in[5];
    float* out = (float*)d_out;

    hipMemsetAsync(out, 0, sizeof(float), stream);
    hipLaunchKernelGGL(pcnn_lp_kernel, dim3(5856), dim3(256), 0, stream,
                       value, dp, W1, b1, W2, b2, out);
}

// Round 2
// 320.320 us; speedup vs baseline: 3.7850x; 3.7850x over previous
//
#include <hip/hip_runtime.h>

#define NC 3
#define NPC 16
#define CIN 19
#define NHID 64
#define IMH 128
#define IMW 128
#define KSZ 171     // CIN*9
#define KPAD 192    // 6 MFMA chunks of 32
#define LDK 200     // LDS row stride in bf16 elems (400 B)

typedef __attribute__((ext_vector_type(8))) short short8;
typedef __attribute__((ext_vector_type(4))) float floatx4;

__device__ __forceinline__ float logsig(float z) {
    return fminf(z, 0.f) - log1pf(expf(-fabsf(z)));
}

__device__ __forceinline__ short f2bf(float f) {
    unsigned u = __float_as_uint(f);
    unsigned r = (u + 0x7fff + ((u >> 16) & 1)) >> 16;
    return (short)r;
}

// Stage 48 consecutive K-entries (k = KB0..KB0+47) of one im2col row into LDS.
// All tap/channel decode is compile-time.
template<int KB0>
__device__ __forceinline__ void im2col48(short* Arow, const float* vb, const float* pb,
                                         int y0, int x0, int gw, int rsh) {
    // Precompute per-dy row offsets/validity and per-dx col offsets/validity
    int rowoff[3]; bool vy[3];
    int coloff[3]; bool vx[3];
    #pragma unroll
    for (int d = 0; d < 3; ++d) {
        int yy = y0 + d - 1;
        vy[d] = (yy >= 0) && (yy < gw);
        rowoff[d] = (yy << rsh) * IMW;
        int xx = x0 + d - 1;
        vx[d] = (xx >= 0) && (xx < gw);
        coloff[d] = (xx << rsh);
    }
    #pragma unroll
    for (int c8 = 0; c8 < 6; ++c8) {
        short8 v8;
        #pragma unroll
        for (int q = 0; q < 8; ++q) {
            const int k = KB0 + c8 * 8 + q;
            float v = 0.f;
            if (k < KSZ) {
                const int ci = k / 9;
                const int tt = k - ci * 9;
                const int dy = tt / 3;
                const int dx = tt - dy * 3;
                const float* src = (ci < NC) ? (vb + ci * IMH * IMW)
                                             : (pb + (ci - NC) * IMH * IMW);
                if (vy[dy] && vx[dx]) v = src[rowoff[dy] + coloff[dx]];
            }
            v8[q] = f2bf(v);
        }
        *(short8*)&Arow[KB0 + c8 * 8] = v8;
    }
}

__global__ __launch_bounds__(512, 2) void pcnn_mfma_kernel(
    const float* __restrict__ value, const float* __restrict__ dp,
    const float* __restrict__ W1, const float* __restrict__ b1,
    const float* __restrict__ W2, const float* __restrict__ b2,
    float* __restrict__ out)
{
    const int bid = blockIdx.x;
    const int tid = threadIdx.x;

    // ---- decode block -> (eval e, batch b, tile t); level geometry ----
    int e, b, t, ow, owsh, rsh, gw, oy0;
    if (bid < 192)       { e = bid >> 6;           int rem = bid & 63;   b = rem >> 1; t = rem & 1;  ow = 16; owsh = 4; rsh = 2; gw = 32;  oy0 = t * 8; }
    else if (bid < 2496) { int u = bid - 192;  e = 3  + (u >> 8);  int rem = u & 255;  b = rem >> 3; t = rem & 7;  ow = 32; owsh = 5; rsh = 1; gw = 64;  oy0 = t * 4; }
    else                 { int u = bid - 2496; e = 12 + (u >> 10); int rem = u & 1023; b = rem >> 5; t = rem & 31; ow = 64; owsh = 6; rsh = 0; gw = 128; oy0 = t * 2; }
    const int r = 1 << rsh;

    int sy0, sx0, cch, s_idx;
    if (e < 3) { sy0 = 0; sx0 = 0; cch = e; s_idx = -1; }
    else {
        int u = e - 3; int s = (u % 9) / 3; cch = u % 3; s_idx = s;
        sy0 = (s == 1) ? 0 : 1;
        sx0 = (s == 2) ? 0 : 1;
    }

    __shared__ __align__(16) short Alds[128 * LDK];   // 51200 B
    __shared__ __align__(16) short Wlds[64 * LDK];    // 25600 B
    __shared__ float wsum[8];

    const float* vb  = value + (size_t)b * NC  * IMH * IMW;
    const float* pb  = dp    + (size_t)b * NPC * IMH * IMW;
    const float* W1n = W1 + (size_t)e * NHID * KSZ;

    // ---- stage masked bf16 weights: Wlds[n][k], taps zeroed per eval mask ----
    {
        const int n  = tid & 63;
        const int j0 = tid >> 6;              // 0..7 (wave-uniform)
        const float* wrow = W1n + n * KSZ;
        #pragma unroll
        for (int i = 0; i < 3; ++i) {
            const int kb = (j0 + i * 8) * 8;  // chunk base, 0..184
            short8 v8;
            #pragma unroll
            for (int q = 0; q < 8; ++q) {
                const int k = kb + q;         // wave-uniform
                float w = 0.f;
                if (k < KSZ) {
                    int ci = k / 9, tt = k - ci * 9, dy = tt / 3, dx = tt - dy * 3;
                    int py = (sy0 + dy - 1) & 1, px = (sx0 + dx - 1) & 1;
                    bool act;
                    if (ci >= NC) act = true;
                    else if (e < 3) act = (py == 0 && px == 0) && (ci < cch);
                    else if (py == 0 && px == 0) act = true;
                    else {
                        int sp = (py == 1 && px == 1) ? 0 : ((py == 0 && px == 1) ? 1 : 2);
                        act = (sp < s_idx) || (sp == s_idx && ci < cch);
                    }
                    if (act) w = wrow[k];
                }
                v8[q] = f2bf(w);
            }
            *(short8*)&Wlds[n * LDK + kb] = v8;
        }
    }

    // ---- im2col A-tile: 128 rows x 192 k (bf16) ----
    const int row = tid & 127;
    const int kq  = tid >> 7;                 // 0..3 (wave-uniform)
    const int oy  = oy0 + (row >> owsh);
    const int ox  = row & (ow - 1);
    const int y0  = sy0 + 2 * oy;
    const int x0  = sx0 + 2 * ox;
    {
        short* Arow = &Alds[row * LDK];
        switch (kq) {
            case 0: im2col48<0>  (Arow, vb, pb, y0, x0, gw, rsh); break;
            case 1: im2col48<48> (Arow, vb, pb, y0, x0, gw, rsh); break;
            case 2: im2col48<96> (Arow, vb, pb, y0, x0, gw, rsh); break;
            default: im2col48<144>(Arow, vb, pb, y0, x0, gw, rsh); break;
        }
    }

    __syncthreads();

    // ---- MFMA: each wave computes rows [w*16, w*16+16) x all 64 cols ----
    const int w    = tid >> 6;
    const int lane = tid & 63;
    const int l15  = lane & 15;
    const int l4   = lane >> 4;

    floatx4 acc[4];
    #pragma unroll
    for (int nb = 0; nb < 4; ++nb) acc[nb] = (floatx4){0.f, 0.f, 0.f, 0.f};

    const int arow = w * 16 + l15;
    #pragma unroll
    for (int kc = 0; kc < 6; ++kc) {
        short8 af = *(const short8*)&Alds[arow * LDK + kc * 32 + l4 * 8];
        #pragma unroll
        for (int nb = 0; nb < 4; ++nb) {
            short8 bf = *(const short8*)&Wlds[(nb * 16 + l15) * LDK + kc * 32 + l4 * 8];
            acc[nb] = __builtin_amdgcn_mfma_f32_16x16x32_bf16(af, bf, acc[nb], 0, 0, 0);
        }
    }

    // ---- epilogue: z = b2 + sum_n W2[n]*relu(C+b1[n]); lp term; reduce ----
    float b1c[4], w2c[4];
    #pragma unroll
    for (int nb = 0; nb < 4; ++nb) {
        const int col = nb * 16 + l15;
        b1c[nb] = b1[e * NHID + col];
        w2c[nb] = W2[e * NHID + col];
    }
    const float bias2 = b2[e];

    float lpsum = 0.f;
    #pragma unroll
    for (int j = 0; j < 4; ++j) {
        float part = 0.f;
        #pragma unroll
        for (int nb = 0; nb < 4; ++nb)
            part += w2c[nb] * fmaxf(acc[nb][j] + b1c[nb], 0.f);
        // reduce across the 16 lanes holding this row's columns
        #pragma unroll
        for (int off = 1; off < 16; off <<= 1) part += __shfl_xor(part, off);
        if (l15 == 0) {
            const int rw  = w * 16 + l4 * 4 + j;
            const int oyj = oy0 + (rw >> owsh);
            const int oxj = rw & (ow - 1);
            const int yj  = sy0 + 2 * oyj;
            const int xj  = sx0 + 2 * oxj;
            const float x = vb[(cch * IMH + yj * r) * IMW + xj * r];
            const float z = part + bias2;
            lpsum += x * logsig(z) + (1.f - x) * logsig(-z);
        }
    }
    lpsum += __shfl_down(lpsum, 32);
    lpsum += __shfl_down(lpsum, 16);

    if (lane == 0) wsum[w] = lpsum;
    __syncthreads();
    if (tid == 0) {
        float s = 0.f;
        #pragma unroll
        for (int i = 0; i < 8; ++i) s += wsum[i];
        atomicAdd(out, s);
    }
}

extern "C" void kernel_launch(void* const* d_in, const int* in_sizes, int n_in,
                              void* d_out, int out_size, void* d_ws, size_t ws_size,
                              hipStream_t stream) {
    const float* value = (const float*)d_in[0];
    const float* dp    = (const float*)d_in[1];
    const float* W1    = (const float*)d_in[2];
    const float* b1    = (const float*)d_in[3];
    const float* W2    = (const float*)d_in[4];
    const float* b2    = (const float*)d_in[5];
    float* out = (float*)d_out;

    hipMemsetAsync(out, 0, sizeof(float), stream);
    hipLaunchKernelGGL(pcnn_mfma_kernel, dim3(11712), dim3(512), 0, stream,
                       value, dp, W1, b1, W2, b2, out);
}

// Round 3
// 290.996 us; speedup vs baseline: 4.1664x; 1.1008x over previous
//
#include <hip/hip_runtime.h>

#define NC 3
#define NPC 16
#define NHID 64
#define IMH 128
#define IMW 128
#define CHP 24          // channel pad in image buffer (19 real + 5 zero)
#define WROW 296        // weight row stride in shorts (9*32 + 8 pad)

typedef __attribute__((ext_vector_type(8))) short short8;
typedef __attribute__((ext_vector_type(4))) float floatx4;

__device__ __forceinline__ float logsig(float z) {
    return fminf(z, 0.f) - log1pf(expf(-fabsf(z)));
}

__device__ __forceinline__ short f2bf(float f) {
    unsigned u = __float_as_uint(f);
    unsigned r = (u + 0x7fff + ((u >> 16) & 1)) >> 16;
    return (short)r;
}

__device__ __forceinline__ short8 zero8() {
    short8 v;
    #pragma unroll
    for (int q = 0; q < 8; ++q) v[q] = 0;
    return v;
}

__device__ __forceinline__ void eval_geom(int e, int& sy0, int& sx0, int& cch, int& s_idx) {
    if (e < 3) { sy0 = 0; sx0 = 0; cch = e; s_idx = -1; }
    else {
        int u = e - 3; int s = (u % 9) / 3; cch = u % 3; s_idx = s;
        sy0 = (s == 1) ? 0 : 1;
        sx0 = (s == 2) ? 0 : 1;
    }
}

__device__ __forceinline__ bool tap_active(int e, int ci, int dy, int dx,
                                           int sy0, int sx0, int cch, int s_idx) {
    if (ci >= NC) return true;
    int py = (sy0 + dy - 1) & 1;
    int px = (sx0 + dx - 1) & 1;
    if (e < 3) return (py == 0 && px == 0) && (ci < cch);
    if (py == 0 && px == 0) return true;
    int sp = (py == 1 && px == 1) ? 0 : ((py == 0 && px == 1) ? 1 : 2);
    return (sp < s_idx) || (sp == s_idx && ci < cch);
}

// ---- prepass 1: fp32 NCHW -> bf16 channel-last [b][y][x][24] ----
__global__ __launch_bounds__(256) void cvt_kernel(
    const float* __restrict__ value, const float* __restrict__ dp,
    short* __restrict__ imgbf)
{
    const int pix = blockIdx.x * 256 + threadIdx.x;   // 524288 total
    const int b   = pix >> 14;
    const int rem = pix & 16383;
    const float* vb = value + (size_t)b * NC  * 16384 + rem;
    const float* pb = dp    + (size_t)b * NPC * 16384 + rem;
    short ch[CHP];
    #pragma unroll
    for (int i = 0; i < NC; ++i)  ch[i]      = f2bf(vb[i * 16384]);
    #pragma unroll
    for (int i = 0; i < NPC; ++i) ch[NC + i] = f2bf(pb[i * 16384]);
    #pragma unroll
    for (int i = 19; i < CHP; ++i) ch[i] = 0;
    short* dst = imgbf + (size_t)pix * CHP;
    #pragma unroll
    for (int g = 0; g < 3; ++g) {
        short8 v;
        #pragma unroll
        for (int q = 0; q < 8; ++q) v[q] = ch[g * 8 + q];
        *(short8*)(dst + g * 8) = v;
    }
}

// ---- prepass 2: masked reordered bf16 weights [e][n][tap*32+ch], row stride 296 ----
__global__ __launch_bounds__(64) void wpk_kernel(
    const float* __restrict__ W1, short* __restrict__ wbf)
{
    const int e = blockIdx.x;
    const int n = threadIdx.x;
    int sy0, sx0, cch, s_idx;
    eval_geom(e, sy0, sx0, cch, s_idx);
    const float* wrow = W1 + ((size_t)e * NHID + n) * 171;
    short* dst = wbf + ((size_t)e * NHID + n) * WROW;
    #pragma unroll
    for (int tap = 0; tap < 9; ++tap) {
        const int dy = tap / 3, dx = tap % 3;
        #pragma unroll
        for (int g = 0; g < 4; ++g) {
            short8 v;
            #pragma unroll
            for (int q = 0; q < 8; ++q) {
                const int ci = g * 8 + q;
                float w = 0.f;
                if (ci < 19 && tap_active(e, ci, dy, dx, sy0, sx0, cch, s_idx))
                    w = wrow[ci * 9 + tap];
                v[q] = f2bf(w);
            }
            *(short8*)(dst + tap * 32 + g * 8) = v;
        }
    }
    *(short8*)(dst + 288) = zero8();
}

// ---- main kernel, templated per level class ----
template<int EBASE, int TSH, int RSH, int OWSH, int NOY, int TY, int TXH>
__global__ __launch_bounds__(256, 2) void pcnn_main(
    const short* __restrict__ imgbf, const short* __restrict__ wbf,
    const float* __restrict__ value, const float* __restrict__ b1,
    const float* __restrict__ W2, const float* __restrict__ b2,
    float* __restrict__ out)
{
    constexpr int GW   = IMH >> RSH;
    constexpr int OW   = 1 << OWSH;
    constexpr int TPIX = TY * 2 * TXH;
    constexpr int CHA  = TPIX * 3;        // 16B chunks in A tile
    constexpr int AELE = TPIX * CHP + 64; // + tail pad (junk-read guard)

    __shared__ __align__(16) short Alds[AELE];
    __shared__ __align__(16) short Wlds[NHID * WROW];
    __shared__ float wsum[4];

    const int bid = blockIdx.x;
    const int tid = threadIdx.x;
    const int e   = EBASE + (bid >> (5 + TSH));
    const int rem = bid & ((1 << (5 + TSH)) - 1);
    const int b   = rem >> TSH;
    const int t   = rem & ((1 << TSH) - 1);
    const int oy0 = t * NOY;

    int sy0, sx0, cch, s_idx;
    eval_geom(e, sy0, sx0, cch, s_idx);
    const int ylo = sy0 + 2 * oy0 - 1;
    const int off = 1 - sx0;

    // ---- stage A tile: x-parity-split channel-last planes ----
    const short* img_b = imgbf + (size_t)b * (IMH * IMW * CHP);
    for (int c = tid; c < CHA + 8; c += 256) {
        short8 v = zero8();
        if (c < CHA) {
            const int pix  = c / 3;
            const int part = c - pix * 3;
            const int xh   = pix % TXH;
            const int typ  = pix / TXH;       // ty*2 + parity
            const int p    = typ & 1;
            const int ty   = typ >> 1;
            const int y    = ylo + ty;
            const int x    = ((xh - off) << 1) + p;
            if ((unsigned)y < GW && (unsigned)x < GW) {
                const short* src = img_b + (((y << RSH) * IMW + (x << RSH)) * CHP + part * 8);
                v = *(const short8*)src;
            }
        }
        *(short8*)&Alds[c * 8] = v;
    }
    // ---- stage prepacked weights (pure copy) ----
    const short* wsrc = wbf + (size_t)e * (NHID * WROW);
    for (int c = tid; c < NHID * WROW / 8; c += 256)
        *(short8*)&Wlds[c * 8] = *(const short8*)&wsrc[c * 8];

    __syncthreads();

    // ---- MFMA: wave w covers rows [w*32, w*32+32) x 64 cols ----
    const int w    = tid >> 6;
    const int lane = tid & 63;
    const int l15  = lane & 15;
    const int l4   = lane >> 4;

    int oyl[2], oxA[2];
    #pragma unroll
    for (int a = 0; a < 2; ++a) {
        const int rowA = w * 32 + a * 16 + l15;
        oyl[a] = rowA >> OWSH;
        oxA[a] = rowA & (OW - 1);
    }

    floatx4 acc[2][4];
    #pragma unroll
    for (int a = 0; a < 2; ++a)
        #pragma unroll
        for (int nb = 0; nb < 4; ++nb)
            acc[a][nb] = (floatx4){0.f, 0.f, 0.f, 0.f};

    #pragma unroll
    for (int tap = 0; tap < 9; ++tap) {
        const int dy  = tap / 3, dx = tap % 3;
        const int sxd = sx0 + dx - 1;
        const int p   = sxd & 1;
        const int cx  = (sxd >> 1) + off;
        short8 a0 = *(const short8*)&Alds[(((2 * oyl[0] + dy) * 2 + p) * TXH + oxA[0] + cx) * CHP + l4 * 8];
        short8 a1 = *(const short8*)&Alds[(((2 * oyl[1] + dy) * 2 + p) * TXH + oxA[1] + cx) * CHP + l4 * 8];
        #pragma unroll
        for (int nb = 0; nb < 4; ++nb) {
            short8 bf = *(const short8*)&Wlds[(nb * 16 + l15) * WROW + tap * 32 + l4 * 8];
            acc[0][nb] = __builtin_amdgcn_mfma_f32_16x16x32_bf16(a0, bf, acc[0][nb], 0, 0, 0);
            acc[1][nb] = __builtin_amdgcn_mfma_f32_16x16x32_bf16(a1, bf, acc[1][nb], 0, 0, 0);
        }
    }

    // ---- epilogue ----
    float b1c[4], w2c[4];
    #pragma unroll
    for (int nb = 0; nb < 4; ++nb) {
        const int col = nb * 16 + l15;
        b1c[nb] = b1[e * NHID + col];
        w2c[nb] = W2[e * NHID + col];
    }
    const float bias2 = b2[e];
    const float* vb = value + ((size_t)b * NC + cch) * 16384;

    float lpsum = 0.f;
    #pragma unroll
    for (int a = 0; a < 2; ++a) {
        #pragma unroll
        for (int j = 0; j < 4; ++j) {
            float part = 0.f;
            #pragma unroll
            for (int nb = 0; nb < 4; ++nb)
                part += w2c[nb] * fmaxf(acc[a][nb][j] + b1c[nb], 0.f);
            #pragma unroll
            for (int o = 1; o < 16; o <<= 1) part += __shfl_xor(part, o);
            if (l15 == 0) {
                const int rw  = w * 32 + a * 16 + l4 * 4 + j;
                const int oyj = oy0 + (rw >> OWSH);
                const int oxj = rw & (OW - 1);
                const int yj  = sy0 + 2 * oyj;
                const int xj  = sx0 + 2 * oxj;
                const float x = vb[((yj << RSH) << 7) + (xj << RSH)];
                const float z = part + bias2;
                lpsum += x * logsig(z) + (1.f - x) * logsig(-z);
            }
        }
    }
    lpsum += __shfl_down(lpsum, 32);
    lpsum += __shfl_down(lpsum, 16);

    if (lane == 0) wsum[w] = lpsum;
    __syncthreads();
    if (tid == 0) atomicAdd(out, wsum[0] + wsum[1] + wsum[2] + wsum[3]);
}

extern "C" void kernel_launch(void* const* d_in, const int* in_sizes, int n_in,
                              void* d_out, int out_size, void* d_ws, size_t ws_size,
                              hipStream_t stream) {
    const float* value = (const float*)d_in[0];
    const float* dp    = (const float*)d_in[1];
    const float* W1    = (const float*)d_in[2];
    const float* b1    = (const float*)d_in[3];
    const float* W2    = (const float*)d_in[4];
    const float* b2    = (const float*)d_in[5];
    float* out = (float*)d_out;

    short* imgbf = (short*)d_ws;                                   // 25.17 MB
    short* wbf   = imgbf + (size_t)32 * IMH * IMW * CHP;           // 0.80 MB

    hipMemsetAsync(out, 0, sizeof(float), stream);
    hipLaunchKernelGGL(cvt_kernel, dim3(2048), dim3(256), 0, stream, value, dp, imgbf);
    hipLaunchKernelGGL(wpk_kernel, dim3(21), dim3(64), 0, stream, W1, wbf);

    // base level: e 0..2, gw=32 (r=4): 3*32*2 = 192 blocks
    hipLaunchKernelGGL((pcnn_main<0, 1, 2, 4, 8, 17, 18>), dim3(192), dim3(256), 0, stream,
                       imgbf, wbf, value, b1, W2, b2, out);
    // mid level: e 3..11, gw=64 (r=2): 9*32*8 = 2304 blocks
    hipLaunchKernelGGL((pcnn_main<3, 3, 1, 5, 4, 9, 34>), dim3(2304), dim3(256), 0, stream,
                       imgbf, wbf, value, b1, W2, b2, out);
    // fine level: e 12..20, gw=128 (r=1): 9*32*32 = 9216 blocks
    hipLaunchKernelGGL((pcnn_main<12, 5, 0, 6, 2, 5, 66>), dim3(9216), dim3(256), 0, stream,
                       imgbf, wbf, value, b1, W2, b2, out);
}

// Round 4
// 173.287 us; speedup vs baseline: 6.9965x; 1.6793x over previous
//
#include <hip/hip_runtime.h>

#define NC 3
#define NPC 16
#define NHID 64
#define IMH 128
#define IMW 128
#define CHP 24          // channels per pixel in image buffer (19 real + 5 zero)
#define WCH 2304        // 16B chunks of one eval's prepacked weights (9*4*64)
#define AOFF 15904      // Wlds offset in smem shorts = max TPIX*CHP+64 (fine: 660*24+64)

typedef __attribute__((ext_vector_type(8))) short short8;
typedef __attribute__((ext_vector_type(4))) float floatx4;

__device__ __forceinline__ float logsig(float z) {
    return fminf(z, 0.f) - log1pf(expf(-fabsf(z)));
}

__device__ __forceinline__ short f2bf(float f) {
    unsigned u = __float_as_uint(f);
    unsigned r = (u + 0x7fff + ((u >> 16) & 1)) >> 16;
    return (short)r;
}

__device__ __forceinline__ short8 zero8() {
    short8 v;
    #pragma unroll
    for (int q = 0; q < 8; ++q) v[q] = 0;
    return v;
}

// 16-lane (DPP row) sum: all lanes end with the row total. VALU pipe, no LDS.
__device__ __forceinline__ float row16sum(float v) {
    v += __int_as_float(__builtin_amdgcn_update_dpp(0, __float_as_int(v), 0x128, 0xf, 0xf, false)); // row_ror:8
    v += __int_as_float(__builtin_amdgcn_update_dpp(0, __float_as_int(v), 0x124, 0xf, 0xf, false)); // row_ror:4
    v += __int_as_float(__builtin_amdgcn_update_dpp(0, __float_as_int(v), 0x122, 0xf, 0xf, false)); // row_ror:2
    v += __int_as_float(__builtin_amdgcn_update_dpp(0, __float_as_int(v), 0x121, 0xf, 0xf, false)); // row_ror:1
    return v;
}

__device__ __forceinline__ void eval_geom(int e, int& sy0, int& sx0, int& cch, int& s_idx) {
    if (e < 3) { sy0 = 0; sx0 = 0; cch = e; s_idx = -1; }
    else {
        int u = e - 3; int s = (u % 9) / 3; cch = u % 3; s_idx = s;
        sy0 = (s == 1) ? 0 : 1;
        sx0 = (s == 2) ? 0 : 1;
    }
}

__device__ __forceinline__ bool tap_active(int e, int ci, int dy, int dx,
                                           int sy0, int sx0, int cch, int s_idx) {
    if (ci >= NC) return true;
    int py = (sy0 + dy - 1) & 1;
    int px = (sx0 + dx - 1) & 1;
    if (e < 3) return (py == 0 && px == 0) && (ci < cch);
    if (py == 0 && px == 0) return true;
    int sp = (py == 1 && px == 1) ? 0 : ((py == 0 && px == 1) ? 1 : 2);
    return (sp < s_idx) || (sp == s_idx && ci < cch);
}

// ---- prepass 1: fp32 NCHW -> bf16 channel-last [b][y][x][24] ----
__global__ __launch_bounds__(256) void cvt_kernel(
    const float* __restrict__ value, const float* __restrict__ dp,
    short* __restrict__ imgbf)
{
    const int pix = blockIdx.x * 256 + threadIdx.x;   // 524288 total
    const int b   = pix >> 14;
    const int rem = pix & 16383;
    const float* vb = value + (size_t)b * NC  * 16384 + rem;
    const float* pb = dp    + (size_t)b * NPC * 16384 + rem;
    short ch[CHP];
    #pragma unroll
    for (int i = 0; i < NC; ++i)  ch[i]      = f2bf(vb[i * 16384]);
    #pragma unroll
    for (int i = 0; i < NPC; ++i) ch[NC + i] = f2bf(pb[i * 16384]);
    #pragma unroll
    for (int i = 19; i < CHP; ++i) ch[i] = 0;
    short* dst = imgbf + (size_t)pix * CHP;
    #pragma unroll
    for (int g = 0; g < 3; ++g) {
        short8 v;
        #pragma unroll
        for (int q = 0; q < 8; ++q) v[q] = ch[g * 8 + q];
        *(short8*)(dst + g * 8) = v;
    }
}

// ---- prepass 2: masked bf16 weights, fragment-major [e][tap][g][n][8] ----
__global__ __launch_bounds__(64) void wpk_kernel(
    const float* __restrict__ W1, short* __restrict__ wbf)
{
    const int e = blockIdx.x;
    const int n = threadIdx.x;
    int sy0, sx0, cch, s_idx;
    eval_geom(e, sy0, sx0, cch, s_idx);
    const float* wrow = W1 + ((size_t)e * NHID + n) * 171;
    short* base = wbf + (size_t)e * (WCH * 8);
    #pragma unroll
    for (int tap = 0; tap < 9; ++tap) {
        const int dy = tap / 3, dx = tap % 3;
        #pragma unroll
        for (int g = 0; g < 4; ++g) {
            short8 v;
            #pragma unroll
            for (int q = 0; q < 8; ++q) {
                const int ci = g * 8 + q;
                float w = 0.f;
                if (ci < 19 && tap_active(e, ci, dy, dx, sy0, sx0, cch, s_idx))
                    w = wrow[ci * 9 + tap];
                v[q] = f2bf(w);
            }
            *(short8*)&base[((tap * 4 + g) * 64 + n) * 8] = v;
        }
    }
}

// ---- per-level worker (inlined into the merged kernel) ----
template<int EBASE, int TSH, int RSH, int OWSH, int NOY, int NT, int TY, int TXH>
__device__ __forceinline__ void run_level(
    int bid, int tid, short* Alds, short* Wlds, float* wsum,
    const short* __restrict__ imgbf, const short* __restrict__ wbf,
    const float* __restrict__ value, const float* __restrict__ b1,
    const float* __restrict__ W2, const float* __restrict__ b2,
    float* __restrict__ out)
{
    constexpr int GW    = IMH >> RSH;
    constexpr int OW    = 1 << OWSH;
    constexpr int TPIX  = TY * 2 * TXH;
    constexpr int NITER = (TPIX + 255) / 256;   // 3 for all levels

    const int e    = EBASE + (bid >> (5 + TSH));
    const int rem  = bid & ((1 << (5 + TSH)) - 1);
    const int b    = rem >> TSH;
    const int tblk = rem & ((1 << TSH) - 1);
    const int oy_start = tblk * (NT * NOY);

    int sy0, sx0, cch, s_idx;
    eval_geom(e, sy0, sx0, cch, s_idx);
    const int off = 1 - sx0;

    const short* img_b = imgbf + (size_t)b * (IMH * IMW * CHP);
    const short* wsrc  = wbf + (size_t)e * (WCH * 8);

    const int w    = tid >> 6;
    const int lane = tid & 63;
    const int l15  = lane & 15;
    const int l4   = lane >> 4;

    // ---- stage W (once per block, linear copy; WCH = 9*256 exactly) ----
    #pragma unroll
    for (int i = 0; i < WCH / 256; ++i) {
        const int c = tid + i * 256;
        *(short8*)&Wlds[c * 8] = *(const short8*)&wsrc[(size_t)c * 8];
    }
    // zero the A tail pad (junk-read guard for last pixel's l4=3 read)
    if (tid < 8) *(short8*)&Alds[TPIX * CHP + tid * 8] = zero8();

    // ---- A stage helpers (reg-staged: load early, write late) ----
    short8 sv[NITER][3];
    auto stage_load = [&](int t) {
        const int ylo = sy0 + 2 * (oy_start + t * NOY) - 1;
        #pragma unroll
        for (int i = 0; i < NITER; ++i) {
            const int pix = tid + i * 256;
            sv[i][0] = zero8(); sv[i][1] = zero8(); sv[i][2] = zero8();
            if (pix < TPIX) {
                const int xh  = pix % TXH;
                const int typ = pix / TXH;
                const int p   = typ & 1;
                const int ty  = typ >> 1;
                const int y   = ylo + ty;
                const int x   = ((xh - off) << 1) + p;
                if ((unsigned)y < GW && (unsigned)x < GW) {
                    const short* src = img_b + (((y << RSH) * IMW + (x << RSH)) * CHP);
                    sv[i][0] = *(const short8*)(src);
                    sv[i][1] = *(const short8*)(src + 8);
                    sv[i][2] = *(const short8*)(src + 16);
                }
            }
        }
    };
    auto stage_write = [&]() {
        #pragma unroll
        for (int i = 0; i < NITER; ++i) {
            const int pix = tid + i * 256;
            if (pix < TPIX) {
                *(short8*)&Alds[pix * CHP]      = sv[i][0];
                *(short8*)&Alds[pix * CHP + 8]  = sv[i][1];
                *(short8*)&Alds[pix * CHP + 16] = sv[i][2];
            }
        }
    };

    stage_load(0);
    __syncthreads();              // W visible, sv[0] loaded (vmcnt drained)
    stage_write();

    // ---- preload B fragments for nb=0,1 into regs (once per block) ----
    short8 breg[9][2];
    #pragma unroll
    for (int tap = 0; tap < 9; ++tap)
        #pragma unroll
        for (int nb = 0; nb < 2; ++nb)
            breg[tap][nb] = *(const short8*)&Wlds[((tap * 4 + l4) * 64 + nb * 16 + l15) * 8];
    __syncthreads();              // A[0] visible

    // ---- per-wave output mapping / epilogue constants ----
    int oyl[2], oxA[2];
    #pragma unroll
    for (int a = 0; a < 2; ++a) {
        const int rowA = w * 32 + a * 16 + l15;
        oyl[a] = rowA >> OWSH;
        oxA[a] = rowA & (OW - 1);
    }
    float b1c[4], w2c[4];
    #pragma unroll
    for (int nb = 0; nb < 4; ++nb) {
        const int col = nb * 16 + l15;
        b1c[nb] = b1[e * NHID + col];
        w2c[nb] = W2[e * NHID + col];
    }
    const float bias2 = b2[e];
    const float* vb = value + ((size_t)b * NC + cch) * (IMH * IMW);

    float lpsum = 0.f;

    for (int t = 0; t < NT; ++t) {
        if (t + 1 < NT) stage_load(t + 1);   // overlap with MFMA phase

        floatx4 acc[2][4];
        #pragma unroll
        for (int a = 0; a < 2; ++a)
            #pragma unroll
            for (int nb = 0; nb < 4; ++nb)
                acc[a][nb] = (floatx4){0.f, 0.f, 0.f, 0.f};

        #pragma unroll
        for (int tap = 0; tap < 9; ++tap) {
            const int dy  = tap / 3, dx = tap % 3;
            const int sxd = sx0 + dx - 1;
            const int p   = sxd & 1;
            const int cx  = (sxd >> 1) + off;
            short8 a0 = *(const short8*)&Alds[(((2 * oyl[0] + dy) * 2 + p) * TXH + oxA[0] + cx) * CHP + l4 * 8];
            short8 a1 = *(const short8*)&Alds[(((2 * oyl[1] + dy) * 2 + p) * TXH + oxA[1] + cx) * CHP + l4 * 8];
            short8 b2f = *(const short8*)&Wlds[((tap * 4 + l4) * 64 + 2 * 16 + l15) * 8];
            short8 b3f = *(const short8*)&Wlds[((tap * 4 + l4) * 64 + 3 * 16 + l15) * 8];
            acc[0][0] = __builtin_amdgcn_mfma_f32_16x16x32_bf16(a0, breg[tap][0], acc[0][0], 0, 0, 0);
            acc[1][0] = __builtin_amdgcn_mfma_f32_16x16x32_bf16(a1, breg[tap][0], acc[1][0], 0, 0, 0);
            acc[0][1] = __builtin_amdgcn_mfma_f32_16x16x32_bf16(a0, breg[tap][1], acc[0][1], 0, 0, 0);
            acc[1][1] = __builtin_amdgcn_mfma_f32_16x16x32_bf16(a1, breg[tap][1], acc[1][1], 0, 0, 0);
            acc[0][2] = __builtin_amdgcn_mfma_f32_16x16x32_bf16(a0, b2f, acc[0][2], 0, 0, 0);
            acc[1][2] = __builtin_amdgcn_mfma_f32_16x16x32_bf16(a1, b2f, acc[1][2], 0, 0, 0);
            acc[0][3] = __builtin_amdgcn_mfma_f32_16x16x32_bf16(a0, b3f, acc[0][3], 0, 0, 0);
            acc[1][3] = __builtin_amdgcn_mfma_f32_16x16x32_bf16(a1, b3f, acc[1][3], 0, 0, 0);
        }

        // ---- epilogue for this tile (VALU-only reduce) ----
        const int oyb = oy_start + t * NOY;
        #pragma unroll
        for (int a = 0; a < 2; ++a) {
            #pragma unroll
            for (int j = 0; j < 4; ++j) {
                float part = 0.f;
                #pragma unroll
                for (int nb = 0; nb < 4; ++nb)
                    part += w2c[nb] * fmaxf(acc[a][nb][j] + b1c[nb], 0.f);
                part = row16sum(part);
                if (l15 == 0) {
                    const int rw  = w * 32 + a * 16 + l4 * 4 + j;
                    const int oyj = oyb + (rw >> OWSH);
                    const int oxj = rw & (OW - 1);
                    const int yj  = sy0 + 2 * oyj;
                    const int xj  = sx0 + 2 * oxj;
                    const float xv = vb[((yj << RSH) * IMW) + (xj << RSH)];
                    const float z  = part + bias2;
                    lpsum += xv * logsig(z) + (1.f - xv) * logsig(-z);
                }
            }
        }

        __syncthreads();                       // everyone done reading A[t]
        if (t + 1 < NT) { stage_write(); __syncthreads(); }
    }

    // ---- block reduce ----
    lpsum += __shfl_down(lpsum, 32);
    lpsum += __shfl_down(lpsum, 16);
    if (lane == 0) wsum[w] = lpsum;
    __syncthreads();
    if (tid == 0) atomicAdd(out, wsum[0] + wsum[1] + wsum[2] + wsum[3]);
}

// ---- merged kernel: fine blocks first, then mid, then base ----
__global__ __launch_bounds__(256, 2) void pcnn_all(
    const short* __restrict__ imgbf, const short* __restrict__ wbf,
    const float* __restrict__ value, const float* __restrict__ b1,
    const float* __restrict__ W2, const float* __restrict__ b2,
    float* __restrict__ out)
{
    __shared__ __align__(16) short smem[AOFF + WCH * 8];
    __shared__ float wsum[4];
    const int bid = blockIdx.x;
    const int tid = threadIdx.x;
    short* Alds = smem;
    short* Wlds = smem + AOFF;

    if (bid < 2304) {
        // fine: e 12..20, gw=128; tile = 2 oy-rows (128 out), NT=4, 8 t-blocks
        run_level<12, 3, 0, 6, 2, 4, 5, 66>(bid, tid, Alds, Wlds, wsum,
                                            imgbf, wbf, value, b1, W2, b2, out);
    } else if (bid < 2880) {
        // mid: e 3..11, gw=64; tile = 4 oy-rows (128 out), NT=4, 2 t-blocks
        run_level<3, 1, 1, 5, 4, 4, 9, 34>(bid - 2304, tid, Alds, Wlds, wsum,
                                           imgbf, wbf, value, b1, W2, b2, out);
    } else {
        // base: e 0..2, gw=32; tile = 8 oy-rows (128 out), NT=2, 1 t-block
        run_level<0, 0, 2, 4, 8, 2, 17, 18>(bid - 2880, tid, Alds, Wlds, wsum,
                                            imgbf, wbf, value, b1, W2, b2, out);
    }
}

extern "C" void kernel_launch(void* const* d_in, const int* in_sizes, int n_in,
                              void* d_out, int out_size, void* d_ws, size_t ws_size,
                              hipStream_t stream) {
    const float* value = (const float*)d_in[0];
    const float* dp    = (const float*)d_in[1];
    const float* W1    = (const float*)d_in[2];
    const float* b1    = (const float*)d_in[3];
    const float* W2    = (const float*)d_in[4];
    const float* b2    = (const float*)d_in[5];
    float* out = (float*)d_out;

    short* imgbf = (short*)d_ws;                                   // 25.17 MB
    short* wbf   = imgbf + (size_t)32 * IMH * IMW * CHP;           // 0.77 MB

    hipMemsetAsync(out, 0, sizeof(float), stream);
    hipLaunchKernelGGL(cvt_kernel, dim3(2048), dim3(256), 0, stream, value, dp, imgbf);
    hipLaunchKernelGGL(wpk_kernel, dim3(21), dim3(64), 0, stream, W1, wbf);
    hipLaunchKernelGGL(pcnn_all, dim3(2976), dim3(256), 0, stream,
                       imgbf, wbf, value, b1, W2, b2, out);
}

// Round 5
// 130.123 us; speedup vs baseline: 9.3174x; 1.3317x over previous
//
#include <hip/hip_runtime.h>

#define NC 3
#define NPC 16
#define NHID 64
#define IMH 128
#define IMW 128
#define CHP 24          // channels per pixel in image buffer (19 real + 5 zero)
#define WHALF 9216      // shorts per eval per weight half (9 taps * 4 g * 32 n * 8)
#define AOFF 15904      // Alds shorts (fine worst: 660*24 + 64 pad)

typedef __attribute__((ext_vector_type(8))) short short8;
typedef __attribute__((ext_vector_type(4))) float floatx4;

__device__ __forceinline__ short f2bf(float f) {
    unsigned u = __float_as_uint(f);
    unsigned r = (u + 0x7fff + ((u >> 16) & 1)) >> 16;
    return (short)r;
}

__device__ __forceinline__ short8 zero8() {
    short8 v;
    #pragma unroll
    for (int q = 0; q < 8; ++q) v[q] = 0;
    return v;
}

// 16-lane (DPP row) sum: all lanes end with the row total. VALU pipe, no LDS.
__device__ __forceinline__ float row16sum(float v) {
    v += __int_as_float(__builtin_amdgcn_update_dpp(0, __float_as_int(v), 0x128, 0xf, 0xf, false)); // row_ror:8
    v += __int_as_float(__builtin_amdgcn_update_dpp(0, __float_as_int(v), 0x124, 0xf, 0xf, false)); // row_ror:4
    v += __int_as_float(__builtin_amdgcn_update_dpp(0, __float_as_int(v), 0x122, 0xf, 0xf, false)); // row_ror:2
    v += __int_as_float(__builtin_amdgcn_update_dpp(0, __float_as_int(v), 0x121, 0xf, 0xf, false)); // row_ror:1
    return v;
}

__device__ __forceinline__ void eval_geom(int e, int& sy0, int& sx0, int& cch, int& s_idx) {
    if (e < 3) { sy0 = 0; sx0 = 0; cch = e; s_idx = -1; }
    else {
        int u = e - 3; int s = (u % 9) / 3; cch = u % 3; s_idx = s;
        sy0 = (s == 1) ? 0 : 1;
        sx0 = (s == 2) ? 0 : 1;
    }
}

__device__ __forceinline__ bool tap_active(int e, int ci, int dy, int dx,
                                           int sy0, int sx0, int cch, int s_idx) {
    if (ci >= NC) return true;
    int py = (sy0 + dy - 1) & 1;
    int px = (sx0 + dx - 1) & 1;
    if (e < 3) return (py == 0 && px == 0) && (ci < cch);
    if (py == 0 && px == 0) return true;
    int sp = (py == 1 && px == 1) ? 0 : ((py == 0 && px == 1) ? 1 : 2);
    return (sp < s_idx) || (sp == s_idx && ci < cch);
}

// ---- prepass 1: fp32 NCHW -> bf16 channel-last [b][y][x][24] ----
__global__ __launch_bounds__(256) void cvt_kernel(
    const float* __restrict__ value, const float* __restrict__ dp,
    short* __restrict__ imgbf)
{
    const int pix = blockIdx.x * 256 + threadIdx.x;   // 524288 total
    const int b   = pix >> 14;
    const int rem = pix & 16383;
    const float* vb = value + (size_t)b * NC  * 16384 + rem;
    const float* pb = dp    + (size_t)b * NPC * 16384 + rem;
    short ch[CHP];
    #pragma unroll
    for (int i = 0; i < NC; ++i)  ch[i]      = f2bf(vb[i * 16384]);
    #pragma unroll
    for (int i = 0; i < NPC; ++i) ch[NC + i] = f2bf(pb[i * 16384]);
    #pragma unroll
    for (int i = 19; i < CHP; ++i) ch[i] = 0;
    short* dst = imgbf + (size_t)pix * CHP;
    #pragma unroll
    for (int g = 0; g < 3; ++g) {
        short8 v;
        #pragma unroll
        for (int q = 0; q < 8; ++q) v[q] = ch[g * 8 + q];
        *(short8*)(dst + g * 8) = v;
    }
}

// ---- prepass 2: masked bf16 weights, fragment-major, split by col half ----
// wbfA: cols 0..31 (kept in regs), wbfB: cols 32..63 (staged to LDS)
__global__ __launch_bounds__(64) void wpk_kernel(
    const float* __restrict__ W1, short* __restrict__ wbfA, short* __restrict__ wbfB)
{
    const int e = blockIdx.x;
    const int n = threadIdx.x;
    int sy0, sx0, cch, s_idx;
    eval_geom(e, sy0, sx0, cch, s_idx);
    const float* wrow = W1 + ((size_t)e * NHID + n) * 171;
    short* dA = wbfA + (size_t)e * WHALF;
    short* dB = wbfB + (size_t)e * WHALF;
    #pragma unroll
    for (int tap = 0; tap < 9; ++tap) {
        const int dy = tap / 3, dx = tap % 3;
        #pragma unroll
        for (int g = 0; g < 4; ++g) {
            short8 v;
            #pragma unroll
            for (int q = 0; q < 8; ++q) {
                const int ci = g * 8 + q;
                float w = 0.f;
                if (ci < 19 && tap_active(e, ci, dy, dx, sy0, sx0, cch, s_idx))
                    w = wrow[ci * 9 + tap];
                v[q] = f2bf(w);
            }
            if (n < 32) *(short8*)&dA[((tap * 4 + g) * 32 + n) * 8] = v;
            else        *(short8*)&dB[((tap * 4 + g) * 32 + (n - 32)) * 8] = v;
        }
    }
}

// ---- per-level worker ----
template<int EBASE, int SY0, int SX0, int TSH, int RSH, int OWSH, int NOY, int NT, int TY, int TXH>
__device__ __forceinline__ void run_level(
    int bid, int tid, short* Alds, short* Wlds, float* wsum,
    const short* __restrict__ imgbf, const short* __restrict__ wbfA,
    const short* __restrict__ wbfB, const float* __restrict__ b1,
    const float* __restrict__ W2, const float* __restrict__ b2,
    float* __restrict__ out)
{
    constexpr int GW    = IMH >> RSH;
    constexpr int OW    = 1 << OWSH;
    constexpr int TPIX  = TY * 2 * TXH;
    constexpr int NITER = (TPIX + 255) / 256;   // 3 for all levels
    constexpr int OFFX  = 1 - SX0;

    const int c    = bid >> (5 + TSH);          // channel index within class
    const int rem  = bid & ((1 << (5 + TSH)) - 1);
    const int b    = rem >> TSH;
    const int tblk = rem & ((1 << TSH) - 1);
    const int e    = EBASE + c;
    const int cch  = c;
    const int oy_start = tblk * (NT * NOY);

    const short* img_b = imgbf + (size_t)b * (IMH * IMW * CHP);
    const short* wA    = wbfA + (size_t)e * WHALF;
    const short* wB    = wbfB + (size_t)e * WHALF;

    const int w    = tid >> 6;
    const int lane = tid & 63;
    const int l15  = lane & 15;
    const int l4   = lane >> 4;

    // ---- stage W cols 32..63 (1152 chunks, linear copy) ----
    #pragma unroll
    for (int i = 0; i < 5; ++i) {
        const int cc = tid + i * 256;
        if (cc < 1152) *(short8*)&Wlds[cc * 8] = *(const short8*)&wB[(size_t)cc * 8];
    }
    if (tid < 8) *(short8*)&Alds[TPIX * CHP + tid * 8] = zero8();

    // ---- breg (cols 0..31) straight from global (L2-resident) ----
    short8 breg[9][2];
    #pragma unroll
    for (int tap = 0; tap < 9; ++tap)
        #pragma unroll
        for (int nb = 0; nb < 2; ++nb)
            breg[tap][nb] = *(const short8*)&wA[((tap * 4 + l4) * 32 + nb * 16 + l15) * 8];

    // ---- A stage helpers (reg-staged: load early, write late) ----
    short8 sv[NITER][3];
    auto stage_load = [&](int t) {
        const int ylo = SY0 + 2 * (oy_start + t * NOY) - 1;
        #pragma unroll
        for (int i = 0; i < NITER; ++i) {
            const int pix = tid + i * 256;
            sv[i][0] = zero8(); sv[i][1] = zero8(); sv[i][2] = zero8();
            if (pix < TPIX) {
                const int xh  = pix % TXH;
                const int typ = pix / TXH;
                const int p   = typ & 1;
                const int ty  = typ >> 1;
                const int y   = ylo + ty;
                const int x   = ((xh - OFFX) << 1) + p;
                if ((unsigned)y < GW && (unsigned)x < GW) {
                    const short* src = img_b + (((y << RSH) * IMW + (x << RSH)) * CHP);
                    sv[i][0] = *(const short8*)(src);
                    sv[i][1] = *(const short8*)(src + 8);
                    sv[i][2] = *(const short8*)(src + 16);
                }
            }
        }
    };
    auto stage_write = [&]() {
        #pragma unroll
        for (int i = 0; i < NITER; ++i) {
            const int pix = tid + i * 256;
            if (pix < TPIX) {
                *(short8*)&Alds[pix * CHP]      = sv[i][0];
                *(short8*)&Alds[pix * CHP + 8]  = sv[i][1];
                *(short8*)&Alds[pix * CHP + 16] = sv[i][2];
            }
        }
    };

    stage_load(0);
    __syncthreads();              // W visible; sv[0] loaded
    stage_write();

    // ---- per-lane bases / epilogue constants ----
    int oyl[2], oxA[2], abase[2];
    #pragma unroll
    for (int a = 0; a < 2; ++a) {
        const int rowA = w * 32 + a * 16 + l15;
        oyl[a]  = rowA >> OWSH;
        oxA[a]  = rowA & (OW - 1);
        abase[a] = (oyl[a] * 4 * TXH + oxA[a]) * CHP + l4 * 8;
    }
    const int wbase = (l4 * 32 + l15) * 8;

    float b1c[4], w2c[4];
    #pragma unroll
    for (int nb = 0; nb < 4; ++nb) {
        const int col = nb * 16 + l15;
        b1c[nb] = b1[e * NHID + col];
        w2c[nb] = W2[e * NHID + col];
    }
    const float bias2 = b2[e];

    __syncthreads();              // A[0] visible

    float lpsum = 0.f;

    for (int t = 0; t < NT; ++t) {
        if (t + 1 < NT) stage_load(t + 1);   // overlap with MFMA phase

        floatx4 acc[2][4];
        #pragma unroll
        for (int a = 0; a < 2; ++a)
            #pragma unroll
            for (int nb = 0; nb < 4; ++nb)
                acc[a][nb] = (floatx4){0.f, 0.f, 0.f, 0.f};

        #pragma unroll
        for (int tap = 0; tap < 9; ++tap) {
            const int dy  = tap / 3, dx = tap % 3;
            const int sxd = SX0 + dx - 1;
            const int p   = sxd & 1;
            const int cx  = (sxd >> 1) + OFFX;
            const int dlt = ((2 * dy + p) * TXH + cx) * CHP;   // compile-time
            short8 a0  = *(const short8*)&Alds[abase[0] + dlt];
            short8 a1  = *(const short8*)&Alds[abase[1] + dlt];
            short8 b2f = *(const short8*)&Wlds[wbase + tap * 1024];
            short8 b3f = *(const short8*)&Wlds[wbase + tap * 1024 + 128];
            acc[0][0] = __builtin_amdgcn_mfma_f32_16x16x32_bf16(a0, breg[tap][0], acc[0][0], 0, 0, 0);
            acc[1][0] = __builtin_amdgcn_mfma_f32_16x16x32_bf16(a1, breg[tap][0], acc[1][0], 0, 0, 0);
            acc[0][1] = __builtin_amdgcn_mfma_f32_16x16x32_bf16(a0, breg[tap][1], acc[0][1], 0, 0, 0);
            acc[1][1] = __builtin_amdgcn_mfma_f32_16x16x32_bf16(a1, breg[tap][1], acc[1][1], 0, 0, 0);
            acc[0][2] = __builtin_amdgcn_mfma_f32_16x16x32_bf16(a0, b2f, acc[0][2], 0, 0, 0);
            acc[1][2] = __builtin_amdgcn_mfma_f32_16x16x32_bf16(a1, b2f, acc[1][2], 0, 0, 0);
            acc[0][3] = __builtin_amdgcn_mfma_f32_16x16x32_bf16(a0, b3f, acc[0][3], 0, 0, 0);
            acc[1][3] = __builtin_amdgcn_mfma_f32_16x16x32_bf16(a1, b3f, acc[1][3], 0, 0, 0);
        }

        // ---- epilogue: z per row (all lanes), then half-wave parallel logsig ----
        float zv[8];
        #pragma unroll
        for (int a = 0; a < 2; ++a) {
            #pragma unroll
            for (int j = 0; j < 4; ++j) {
                float part = 0.f;
                #pragma unroll
                for (int nb = 0; nb < 4; ++nb)
                    part += w2c[nb] * fmaxf(acc[a][nb][j] + b1c[nb], 0.f);
                zv[a * 4 + j] = row16sum(part);
            }
        }

        if (l15 < 8) {
            // zsel = zv[l15] via cndmask tree (static indices only)
            const float s01 = (l15 & 1) ? zv[1] : zv[0];
            const float s23 = (l15 & 1) ? zv[3] : zv[2];
            const float s45 = (l15 & 1) ? zv[5] : zv[4];
            const float s67 = (l15 & 1) ? zv[7] : zv[6];
            const float s03 = (l15 & 2) ? s23 : s01;
            const float s47 = (l15 & 2) ? s67 : s45;
            const float zs  = ((l15 & 4) ? s47 : s03) + bias2;
            // row handled by this lane
            const int rwg    = w * 32 + ((l15 >> 2) << 4) + (l4 << 2) + (l15 & 3);
            const int oy_rel = rwg >> OWSH;
            const int oxj    = rwg & (OW - 1);
            // xv (bf16) from A tile center tap
            const int pix = ((2 * oy_rel + 1) * 2 + SX0) * TXH + oxj + OFFX;
            const unsigned short hv = *(const unsigned short*)&Alds[pix * CHP + cch];
            const float xv = __uint_as_float(((unsigned)hv) << 16);
            // term = xv*z + logsig(-z);  logsig(-z) = min(-z,0) - log1p(exp(-|z|))
            const float az  = fabsf(zs);
            const float t2  = __builtin_amdgcn_exp2f(-1.442695041f * az);
            const float l1p = 0.69314718056f * __builtin_amdgcn_logf(1.f + t2);
            lpsum += xv * zs + fminf(-zs, 0.f) - l1p;
        }

        __syncthreads();                       // everyone done reading A[t]
        if (t + 1 < NT) { stage_write(); __syncthreads(); }
    }

    // ---- block reduce ----
    lpsum += __shfl_down(lpsum, 32);
    lpsum += __shfl_down(lpsum, 16);
    lpsum += __shfl_down(lpsum, 8);
    lpsum += __shfl_down(lpsum, 4);
    lpsum += __shfl_down(lpsum, 2);
    lpsum += __shfl_down(lpsum, 1);
    if (lane == 0) wsum[w] = lpsum;
    __syncthreads();
    if (tid == 0) atomicAdd(out, wsum[0] + wsum[1] + wsum[2] + wsum[3]);
}

// ---- merged kernel: 7 parity-class instantiations, fine first ----
__global__ __launch_bounds__(256, 3) void pcnn_all(
    const short* __restrict__ imgbf, const short* __restrict__ wbfA,
    const short* __restrict__ wbfB, const float* __restrict__ b1,
    const float* __restrict__ W2, const float* __restrict__ b2,
    float* __restrict__ out)
{
    __shared__ __align__(16) short smem[AOFF + WHALF];
    __shared__ float wsum[4];
    const int bid = blockIdx.x;
    const int tid = threadIdx.x;
    short* Alds = smem;
    short* Wlds = smem + AOFF;

    //            EBASE SY SX TSH RSH OWSH NOY NT TY TXH
    if (bid < 768)
        run_level<12, 1, 1, 3, 0, 6, 2, 4, 5, 66>(bid,        tid, Alds, Wlds, wsum, imgbf, wbfA, wbfB, b1, W2, b2, out);
    else if (bid < 1536)
        run_level<15, 0, 1, 3, 0, 6, 2, 4, 5, 66>(bid - 768,  tid, Alds, Wlds, wsum, imgbf, wbfA, wbfB, b1, W2, b2, out);
    else if (bid < 2304)
        run_level<18, 1, 0, 3, 0, 6, 2, 4, 5, 66>(bid - 1536, tid, Alds, Wlds, wsum, imgbf, wbfA, wbfB, b1, W2, b2, out);
    else if (bid < 2496)
        run_level<3,  1, 1, 1, 1, 5, 4, 4, 9, 34>(bid - 2304, tid, Alds, Wlds, wsum, imgbf, wbfA, wbfB, b1, W2, b2, out);
    else if (bid < 2688)
        run_level<6,  0, 1, 1, 1, 5, 4, 4, 9, 34>(bid - 2496, tid, Alds, Wlds, wsum, imgbf, wbfA, wbfB, b1, W2, b2, out);
    else if (bid < 2880)
        run_level<9,  1, 0, 1, 1, 5, 4, 4, 9, 34>(bid - 2688, tid, Alds, Wlds, wsum, imgbf, wbfA, wbfB, b1, W2, b2, out);
    else
        run_level<0,  0, 0, 0, 2, 4, 8, 2, 17, 18>(bid - 2880, tid, Alds, Wlds, wsum, imgbf, wbfA, wbfB, b1, W2, b2, out);
}

extern "C" void kernel_launch(void* const* d_in, const int* in_sizes, int n_in,
                              void* d_out, int out_size, void* d_ws, size_t ws_size,
                              hipStream_t stream) {
    const float* value = (const float*)d_in[0];
    const float* dp    = (const float*)d_in[1];
    const float* W1    = (const float*)d_in[2];
    const float* b1    = (const float*)d_in[3];
    const float* W2    = (const float*)d_in[4];
    const float* b2    = (const float*)d_in[5];
    float* out = (float*)d_out;

    short* imgbf = (short*)d_ws;                                   // 25.17 MB
    short* wbfA  = imgbf + (size_t)32 * IMH * IMW * CHP;           // 387 KB
    short* wbfB  = wbfA + (size_t)21 * WHALF;                      // 387 KB

    hipMemsetAsync(out, 0, sizeof(float), stream);
    hipLaunchKernelGGL(cvt_kernel, dim3(2048), dim3(256), 0, stream, value, dp, imgbf);
    hipLaunchKernelGGL(wpk_kernel, dim3(21), dim3(64), 0, stream, W1, wbfA, wbfB);
    hipLaunchKernelGGL(pcnn_all, dim3(2976), dim3(256), 0, stream,
                       imgbf, wbfA, wbfB, b1, W2, b2, out);
}